// Round 7
// baseline (482.958 us; speedup 1.0000x reference)
//
#include <hip/hip_runtime.h>
#include <math.h>

typedef __attribute__((ext_vector_type(8)))  short  short8;    // 8 bf16
typedef __attribute__((ext_vector_type(4)))  short  svec4;     // 4 bf16 (b64)
typedef __attribute__((ext_vector_type(4)))  float  floatx4;
typedef __attribute__((ext_vector_type(16))) float  floatx16;
typedef __attribute__((ext_vector_type(2)))  float  floatx2;
typedef __attribute__((ext_vector_type(2)))  unsigned uintx2;

__device__ __forceinline__ short bf16rne(float f) {
    unsigned u = __float_as_uint(f);
    unsigned r = (u + 0x7FFFu + ((u >> 16) & 1u)) >> 16;
    return (short)r;
}
__device__ __forceinline__ unsigned pk2(float a, float b) {
#if __has_builtin(__builtin_amdgcn_cvt_pk_bf16_f32)
    auto t = __builtin_amdgcn_cvt_pk_bf16_f32(a, b);
    unsigned u; __builtin_memcpy(&u, &t, 4); return u;
#else
    return (unsigned)(unsigned short)bf16rne(a) |
           ((unsigned)(unsigned short)bf16rne(b) << 16);
#endif
}
__device__ __forceinline__ floatx2 pkmax0(floatx2 a) {
#if __has_builtin(__builtin_elementwise_max)
    floatx2 z = {0.f, 0.f};
    return __builtin_elementwise_max(a, z);
#else
    floatx2 r; r.x = fmaxf(a.x, 0.f); r.y = fmaxf(a.y, 0.f); return r;
#endif
}

// ws: [0,8192) feat_sum; frags at 8192: 11 x 64 x 16B (W1a, W1b, B2[0..8]);
// conv1 C-init bias at +11264 (64 x float4); conv2 bias at +12288 (64 x f32)
#define WS_FRAG_OFF  8192
#define WS_BIAS1_OFF (WS_FRAG_OFF + 11 * 64 * 16)
#define WS_BIAS2_OFF (WS_BIAS1_OFF + 64 * 16)

#define PLANE_B 9792             // bytes per h1 ic-half plane chunk (18*34*16)

// ---------------------------------------------------------------------------
// Setup: build MFMA weight fragments + bias tables, zero feat & out-load.
// ---------------------------------------------------------------------------
__global__ __launch_bounds__(256) void build_frags_kernel(
    const float* __restrict__ w1,   // (16,3,9) = [oc][c][p]
    const float* __restrict__ b1,   // (16,)
    const float* __restrict__ w2,   // (32,16,9)
    const float* __restrict__ b2,   // (32,)
    void* __restrict__ ws,
    float* __restrict__ out)        // gates(4096) + load(64)
{
    const int t = threadIdx.x;
    float* feat = (float*)ws;
    for (int i = t; i < 2048; i += 256) feat[i] = 0.0f;
    if (t >= 64 && t < 128) out[4096 + (t - 64)] = 0.0f;

    if (t < 64) {
        const int lane = t;
        const int q = lane >> 4, ml = lane & 15;
        const int n32 = lane & 31, half = lane >> 5;
        short8* F = (short8*)((char*)ws + WS_FRAG_OFF);

        short8 W1a;
#pragma unroll
        for (int j = 0; j < 8; ++j) {
            int p = q * 2 + (j >> 2), c = j & 3;
            W1a[j] = (c < 3) ? bf16rne(w1[ml * 27 + c * 9 + p]) : (short)0;
        }
        F[0 * 64 + lane] = W1a;

        short8 W1b;
#pragma unroll
        for (int j = 0; j < 8; ++j) {
            W1b[j] = (q == 0 && j < 3) ? bf16rne(w1[ml * 27 + j * 9 + 8])
                                       : (short)0;
        }
        F[1 * 64 + lane] = W1b;

#pragma unroll
        for (int s = 0; s < 9; ++s) {
            short8 Bs;
#pragma unroll
            for (int j = 0; j < 8; ++j) {
                int ic = half * 8 + j;
                Bs[j] = bf16rne(w2[(n32 * 16 + ic) * 9 + s]);
            }
            F[(2 + s) * 64 + lane] = Bs;
        }
        floatx4 bv;
#pragma unroll
        for (int r = 0; r < 4; ++r) bv[r] = b1[q * 4 + r];
        ((floatx4*)((char*)ws + WS_BIAS1_OFF))[lane] = bv;
        ((float*)((char*)ws + WS_BIAS2_OFF))[lane] = b2[n32];
    }
}

// one conv1 micro-tile: 3 b64 gathers, 2 MFMA, packed relu, pack, b64 store.
__device__ __forceinline__ void conv1_tile(
    char* __restrict__ wptr, const char* __restrict__ inb,
    const int* lcB, int gbyte, int wbyte, bool valid, bool wmask,
    short8 W1a, short8 W1b, floatx4 biasv)
{
    svec4 r0 = *(const svec4*)(inb + gbyte + lcB[0]);
    svec4 r1 = *(const svec4*)(inb + gbyte + lcB[1]);
    svec4 r2 = *(const svec4*)(inb + gbyte + lcB[2]);
    short8 Bx = __builtin_shufflevector(r0, r1, 0, 1, 2, 3, 4, 5, 6, 7);
    short8 By = __builtin_shufflevector(r2, r0, 0, 1, 2, 3, 4, 5, 6, 7);
    floatx4 acc = __builtin_amdgcn_mfma_f32_16x16x32_bf16(W1a, Bx, biasv,
                                                          0, 0, 0);
    acc = __builtin_amdgcn_mfma_f32_16x16x32_bf16(W1b, By, acc, 0, 0, 0);
    floatx2 lo = {acc[0], acc[1]}, hi = {acc[2], acc[3]};
    lo = pkmax0(lo); hi = pkmax0(hi);
    if (!valid) { floatx2 z = {0.f, 0.f}; lo = z; hi = z; }
    if (wmask) {
        uintx2 w; w.x = pk2(lo.x, lo.y); w.y = pk2(hi.x, hi.y);
        *(uintx2*)(wptr + wbyte) = w;
    }
}

// conv1 over one 18-row h1 chunk (local rows 0..17 = absolute r0..r0+17):
// 36 row-units + 2 col-units + corner(4px), distributed over 4 waves.
__device__ __forceinline__ void conv1_chunk(
    int r0, bool border, int tx, int ty, int wv, int q, int ml,
    const int* lcB, char* __restrict__ s_h1, const char* __restrict__ inb,
    short8 W1a, short8 W1b, floatx4 biasv)
{
    char* wptr = s_h1 + (q >> 1) * PLANE_B + (q & 1) * 8;
    const int mlb = ml * 8, ml16 = ml * 16;
    const int gbase = r0 * 288;
    if (!border) {
#pragma unroll
        for (int i = 0; i < 9; ++i) {
            int u = wv * 9 + i, row = u >> 1, ch = u & 1;
            conv1_tile(wptr, inb, lcB, gbase + row * 288 + ch * 128 + mlb,
                       row * 544 + ch * 256 + ml16, true, true,
                       W1a, W1b, biasv);
        }
        if (wv < 2) {      // col unit: col 32+wv, rows 0..15
            int col = 32 + wv;
            conv1_tile(wptr, inb, lcB, gbase + ml * 288 + col * 8,
                       ml * 544 + col * 16, true, true, W1a, W1b, biasv);
        }
        if (wv == 2) {     // corner 4 px: local rows 16-17 x cols 32-33
            int ml2 = ml & 3;
            int iy = 16 + (ml2 >> 1), ix = 32 + (ml2 & 1);
            conv1_tile(wptr, inb, lcB, gbase + iy * 288 + ix * 8,
                       (iy * 34 + ix) * 16, true, ml < 4, W1a, W1b, biasv);
        }
    } else {
        const int gyb = ty * 32 - 1 + r0;
        const bool gxOK0 = (unsigned)(tx * 32 - 1 + ml) < 256u;
        const bool gxOK1 = (unsigned)(tx * 32 + 15 + ml) < 256u;
#pragma unroll
        for (int i = 0; i < 9; ++i) {
            int u = wv * 9 + i, row = u >> 1, ch = u & 1;
            bool ok = ((unsigned)(gyb + row) < 256u) & (ch ? gxOK1 : gxOK0);
            conv1_tile(wptr, inb, lcB, gbase + row * 288 + ch * 128 + mlb,
                       row * 544 + ch * 256 + ml16, ok, true,
                       W1a, W1b, biasv);
        }
        if (wv < 2) {
            int col = 32 + wv;
            bool ok = ((unsigned)(gyb + ml) < 256u) &
                      ((unsigned)(tx * 32 - 1 + col) < 256u);
            conv1_tile(wptr, inb, lcB, gbase + ml * 288 + col * 8,
                       ml * 544 + col * 16, ok, true, W1a, W1b, biasv);
        }
        if (wv == 2) {
            int ml2 = ml & 3;
            int iy = 16 + (ml2 >> 1), ix = 32 + (ml2 & 1);
            bool ok = ((unsigned)(gyb + iy) < 256u) &
                      ((unsigned)(tx * 32 - 1 + ix) < 256u);
            conv1_tile(wptr, inb, lcB, gbase + iy * 288 + ix * 8,
                       (iy * 34 + ix) * 16, ok, ml < 4, W1a, W1b, biasv);
        }
    }
}

// conv2 over one chunk: wave = 4 chained 32-px tiles (2 rows x 16 cols),
// sliding 3x3 A-window; out local rows 0..15 read h1 slots 0..17.
__device__ __forceinline__ float conv2_chunk(
    int wv, int n32, int half, const char* __restrict__ s_h1,
    const short8* __restrict__ B2, floatx16 bias16)
{
    const int prow0 = n32 >> 4, pcol = n32 & 15;
    const int ch = wv >> 1, rbase = (wv & 1) * 8;
    const int ox = ch * 16 + pcol;
    const char* pl = s_h1 + half * PLANE_B;
    int pb = ((rbase + prow0) * 34 + ox) * 16;
    short8 Af[3][3];
#pragma unroll
    for (int ky = 0; ky < 3; ++ky)
#pragma unroll
        for (int kx = 0; kx < 3; ++kx)
            Af[ky][kx] = *(const short8*)(pl + pb + (ky * 34 + kx) * 16);

    floatx2 p2 = {0.f, 0.f};
#pragma unroll
    for (int it = 0; it < 4; ++it) {
        const int rb = (2 * it) % 3;
        floatx16 acc = __builtin_amdgcn_mfma_f32_32x32x16_bf16(
                Af[rb][0], B2[0], bias16, 0, 0, 0);
#pragma unroll
        for (int s = 1; s < 9; ++s) {
            const int ky = s / 3, kx = s % 3;
            acc = __builtin_amdgcn_mfma_f32_32x32x16_bf16(
                    Af[(rb + ky) % 3][kx], B2[s], acc, 0, 0, 0);
        }
#pragma unroll
        for (int r = 0; r < 16; r += 2) {
            floatx2 a2 = {acc[r], acc[r + 1]};
            p2 += pkmax0(a2);
        }
        if (it < 3) {
            pb += 1088;   // advance 2 h1 rows
#pragma unroll
            for (int kx = 0; kx < 3; ++kx) {
                Af[rb][kx] = *(const short8*)(pl + pb + (1 * 34 + kx) * 16);
                Af[(rb + 1) % 3][kx] =
                    *(const short8*)(pl + pb + (2 * 34 + kx) * 16);
            }
        }
    }
    return p2.x + p2.y;
}

// ---------------------------------------------------------------------------
// Kernel A: 32x32 output tile per block, h1 processed in TWO 18-row chunks
// (rows 16-17 recomputed) so the h1 buffer is 19.6 KB instead of 37 KB:
// total LDS 30.5 KB -> 5 resident blocks/CU (20 waves) vs 3 (12). Same grid,
// same staging, same per-block prologue as the verified 68.4 us baseline --
// isolates residency/latency-hiding as the single variable.
// grid (8,8,64), 256 threads = 4 waves.
// ---------------------------------------------------------------------------
__global__ __launch_bounds__(256, 5) void conv_feat_kernel(
    const float* __restrict__ x,      // (64,3,256,256)
    const void*  __restrict__ ws_ro,
    float* __restrict__ feat_sum)     // (64,32)
{
    __shared__ short s_in4[36 * 36 * 4];   // bf16 [r][col][c pad4] (10368 B)
    __shared__ short s_h1[2 * 4896];       // two 18-row ic-half chunks (19584 B)
    __shared__ float s_part[4][32];

    const int t    = threadIdx.x;
    const int lane = t & 63, wv = t >> 6;
    const int q    = lane >> 4, ml = lane & 15;
    const int n32  = lane & 31, half = lane >> 5;
    const int tx = blockIdx.x, ty = blockIdx.y, b = blockIdx.z;
    const bool border = (tx == 0) | (tx == 7) | (ty == 0) | (ty == 7);

    // ---- weight fragments / biases ----
    const short8* F = (const short8*)((const char*)ws_ro + WS_FRAG_OFF);
    short8 W1a = F[0 * 64 + lane];
    short8 W1b = F[1 * 64 + lane];
    short8 B2[9];
#pragma unroll
    for (int s = 0; s < 9; ++s) B2[s] = F[(2 + s) * 64 + lane];
    floatx4 biasv = ((const floatx4*)((const char*)ws_ro + WS_BIAS1_OFF))[lane];
    float   b2v   = ((const float*)((const char*)ws_ro + WS_BIAS2_OFF))[lane];
    floatx16 bias16;
#pragma unroll
    for (int r = 0; r < 16; ++r) bias16[r] = b2v;

    // conv1 gather byte offsets (row stride 36 px * 8 B): positions q*2,q*2+1,8
    int lcB[3];
    {
        int p0 = q * 2, p1 = q * 2 + 1;
        lcB[0] = ((p0 / 3) * 36 + p0 % 3) * 8;
        lcB[1] = ((p1 / 3) * 36 + p1 % 3) * 8;
        lcB[2] = (2 * 36 + 2) * 8;
    }

    // ---- stage full input tile as bf16 [r][col][4] (halo 2): 36x36 ----
    const int gy0 = ty * 32 - 2, gx0 = tx * 32 - 2;
    const float* xb = x + (size_t)b * 3 * 65536;
    if (!border) {
        for (int i = t; i < 1296; i += 256) {
            int r = i / 36, c = i - r * 36;
            const float* p = xb + (gy0 + r) * 256 + gx0 + c;
            float v0 = p[0], v1 = p[65536], v2 = p[131072];
            uintx2 w; w.x = pk2(v0, v1); w.y = pk2(v2, 0.f);
            *(uintx2*)&s_in4[i * 4] = w;
        }
    } else {
        for (int i = t; i < 1296; i += 256) {
            int r = i / 36, c = i - r * 36;
            int gy = gy0 + r, gx = gx0 + c;
            float v0 = 0.f, v1 = 0.f, v2 = 0.f;
            if ((unsigned)gy < 256u && (unsigned)gx < 256u) {
                const float* p = xb + gy * 256 + gx;
                v0 = p[0]; v1 = p[65536]; v2 = p[131072];
            }
            uintx2 w; w.x = pk2(v0, v1); w.y = pk2(v2, 0.f);
            *(uintx2*)&s_in4[i * 4] = w;
        }
    }
    __syncthreads();

    // ---- chunk A: h1 rows 0..17 -> conv2 out rows 0..15 ----
    conv1_chunk(0, border, tx, ty, wv, q, ml, lcB, (char*)s_h1,
                (const char*)s_in4, W1a, W1b, biasv);
    __syncthreads();
    float part = conv2_chunk(wv, n32, half, (const char*)s_h1, B2, bias16);
    __syncthreads();   // drain conv2 reads before chunk B overwrites h1

    // ---- chunk B: h1 rows 16..33 -> conv2 out rows 16..31 ----
    conv1_chunk(16, border, tx, ty, wv, q, ml, lcB, (char*)s_h1,
                (const char*)s_in4, W1a, W1b, biasv);
    __syncthreads();
    part += conv2_chunk(wv, n32, half, (const char*)s_h1, B2, bias16);

    part += __shfl_xor(part, 32);
    if (lane < 32) s_part[wv][n32] = part;
    __syncthreads();
    if (t < 32) {
        float ssum = s_part[0][t] + s_part[1][t] + s_part[2][t] + s_part[3][t];
        atomicAdd(feat_sum + b * 32 + t, ssum);
    }
}

// ---------------------------------------------------------------------------
// Kernel B: gating. One block per batch row, 64 threads (= experts, 1 wave).
// ---------------------------------------------------------------------------
__global__ __launch_bounds__(64) void router_gate_kernel(
    const int* __restrict__ task_id,
    const float* __restrict__ noise,
    const float* __restrict__ mlp_w1,
    const float* __restrict__ mlp_b1,
    const float* __restrict__ mlp_w2,
    const float* __restrict__ mlp_b2,
    const float* __restrict__ deg_w,
    const float* __restrict__ deg_b,
    const float* __restrict__ keys,
    const float* __restrict__ gate_w,
    const float* __restrict__ gate_b,
    const float* __restrict__ noise_w,
    const float* __restrict__ noise_b,
    const float* __restrict__ feat_sum,
    float* __restrict__ out)
{
    const int b = blockIdx.x;
    const int e = threadIdx.x;

    __shared__ float s_te[32];
    __shared__ float s_comb[32];
    __shared__ float s_ew[64];

    if (e < 32) {
        float tf = (float)task_id[b];
        s_te[e] = fmaxf(tf * mlp_w1[e] + mlp_b1[e], 0.0f);
    }
    __syncthreads();
    if (e < 32) {
        float acc = mlp_b2[e];
        for (int k = 0; k < 32; ++k) acc += s_te[k] * mlp_w2[k * 32 + e];
        float dacc = deg_b[e];
        for (int c = 0; c < 32; ++c)
            dacc += (feat_sum[b * 32 + c] * (1.0f / 65536.0f)) * deg_w[c * 32 + e];
        s_comb[e] = acc + 0.2f * dacc;  // ALPHA = 0.8
    }
    __syncthreads();

    float s = 0.0f;
    for (int d = 0; d < 32; ++d) s += s_comb[d] * keys[e * 32 + d];
    s *= 0.17677669529663687f;  // 1/sqrt(32)

    float m = s;
    for (int off = 32; off; off >>= 1) m = fmaxf(m, __shfl_xor(m, off));
    float p = expf(s - m);
    float sum = p;
    for (int off = 32; off; off >>= 1) sum += __shfl_xor(sum, off);
    float w = p / sum;
    s_ew[e] = w;
    __syncthreads();

    float cl = gate_b[e], nz = noise_b[e];
    for (int k = 0; k < 64; ++k) {
        float ewk = s_ew[k];
        cl += ewk * gate_w[k * 64 + e];
        nz += ewk * noise_w[k * 64 + e];
    }
    float sp = (nz > 20.0f) ? nz : log1pf(expf(nz));
    float logit = cl + noise[b * 64 + e] * (sp + 0.01f);

    float v0 = logit; int i0 = e;
    for (int off = 32; off; off >>= 1) {
        float ov = __shfl_xor(v0, off);
        int   oi = __shfl_xor(i0, off);
        if (ov > v0 || (ov == v0 && oi < i0)) { v0 = ov; i0 = oi; }
    }
    float v1 = (e == i0) ? -INFINITY : logit; int i1 = e;
    for (int off = 32; off; off >>= 1) {
        float ov = __shfl_xor(v1, off);
        int   oi = __shfl_xor(i1, off);
        if (ov > v1 || (ov == v1 && oi < i1)) { v1 = ov; i1 = oi; }
    }

    float e1 = expf(v1 - v0);
    float g0 = 1.0f / (1.0f + e1);
    float g1 = e1 / (1.0f + e1);

    float g = (e == i0) ? g0 : (e == i1) ? g1 : 0.0f;
    out[b * 64 + e] = g;
    if (g != 0.0f) atomicAdd(out + 64 * 64 + e, g);
}

extern "C" void kernel_launch(void* const* d_in, const int* in_sizes, int n_in,
                              void* d_out, int out_size, void* d_ws, size_t ws_size,
                              hipStream_t stream) {
    const int*   task_id = (const int*)d_in[0];
    const float* x       = (const float*)d_in[1];
    const float* noise   = (const float*)d_in[2];
    const float* mlp_w1  = (const float*)d_in[3];
    const float* mlp_b1  = (const float*)d_in[4];
    const float* mlp_w2  = (const float*)d_in[5];
    const float* mlp_b2  = (const float*)d_in[6];
    const float* conv1_w = (const float*)d_in[7];
    const float* conv1_b = (const float*)d_in[8];
    const float* conv2_w = (const float*)d_in[9];
    const float* conv2_b = (const float*)d_in[10];
    const float* deg_w   = (const float*)d_in[11];
    const float* deg_b   = (const float*)d_in[12];
    const float* keys    = (const float*)d_in[13];
    const float* gate_w  = (const float*)d_in[14];
    const float* gate_b  = (const float*)d_in[15];
    const float* noise_w = (const float*)d_in[16];
    const float* noise_b = (const float*)d_in[17];

    float* out  = (float*)d_out;
    float* feat = (float*)d_ws;

    build_frags_kernel<<<1, 256, 0, stream>>>(conv1_w, conv1_b, conv2_w,
                                              conv2_b, d_ws, out);
    dim3 gridA(8, 8, 64);
    conv_feat_kernel<<<gridA, 256, 0, stream>>>(x, d_ws, feat);
    router_gate_kernel<<<64, 64, 0, stream>>>(
        task_id, noise, mlp_w1, mlp_b1, mlp_w2, mlp_b2, deg_w, deg_b, keys,
        gate_w, gate_b, noise_w, noise_b, feat, out);
}

// Round 8
// 172.824 us; speedup vs baseline: 2.7945x; 2.7945x over previous
//
#include <hip/hip_runtime.h>
#include <math.h>

typedef __attribute__((ext_vector_type(8)))  short  short8;    // 8 bf16
typedef __attribute__((ext_vector_type(4)))  short  svec4;     // 4 bf16 (b64)
typedef __attribute__((ext_vector_type(4)))  float  floatx4;
typedef __attribute__((ext_vector_type(16))) float  floatx16;
typedef __attribute__((ext_vector_type(2)))  float  floatx2;
typedef __attribute__((ext_vector_type(2)))  unsigned uintx2;

__device__ __forceinline__ short bf16rne(float f) {
    unsigned u = __float_as_uint(f);
    unsigned r = (u + 0x7FFFu + ((u >> 16) & 1u)) >> 16;
    return (short)r;
}
__device__ __forceinline__ unsigned pk2(float a, float b) {
#if __has_builtin(__builtin_amdgcn_cvt_pk_bf16_f32)
    auto t = __builtin_amdgcn_cvt_pk_bf16_f32(a, b);
    unsigned u; __builtin_memcpy(&u, &t, 4); return u;
#else
    return (unsigned)(unsigned short)bf16rne(a) |
           ((unsigned)(unsigned short)bf16rne(b) << 16);
#endif
}
__device__ __forceinline__ floatx2 pkmax0(floatx2 a) {
#if __has_builtin(__builtin_elementwise_max)
    floatx2 z = {0.f, 0.f};
    return __builtin_elementwise_max(a, z);
#else
    floatx2 r; r.x = fmaxf(a.x, 0.f); r.y = fmaxf(a.y, 0.f); return r;
#endif
}

// ws: [0,8192) feat_sum; frags at 8192: 11 x 64 x 16B (W1a, W1b, B2[0..8]);
// conv1 C-init bias at +11264 (64 x float4); conv2 bias at +12288 (64 x f32)
#define WS_FRAG_OFF  8192
#define WS_BIAS1_OFF (WS_FRAG_OFF + 11 * 64 * 16)
#define WS_BIAS2_OFF (WS_BIAS1_OFF + 64 * 16)

#define PLANE_B 18496            // bytes per h1 ic-half plane (34*34*16)

// ---------------------------------------------------------------------------
// Setup: build MFMA weight fragments + bias tables, zero feat & out-load.
// conv1 K-map: k = p*4 + c for positions p=0..7 (MFMA #1); position 8 in
// MFMA #2 at k=c (rest zero). c=3 is a zero pad channel.
// ---------------------------------------------------------------------------
__global__ __launch_bounds__(256) void build_frags_kernel(
    const float* __restrict__ w1,   // (16,3,9) = [oc][c][p]
    const float* __restrict__ b1,   // (16,)
    const float* __restrict__ w2,   // (32,16,9)
    const float* __restrict__ b2,   // (32,)
    void* __restrict__ ws,
    float* __restrict__ out)        // gates(4096) + load(64)
{
    const int t = threadIdx.x;
    float* feat = (float*)ws;
    for (int i = t; i < 2048; i += 256) feat[i] = 0.0f;
    if (t >= 64 && t < 128) out[4096 + (t - 64)] = 0.0f;

    if (t < 64) {
        const int lane = t;
        const int q = lane >> 4, ml = lane & 15;
        const int n32 = lane & 31, half = lane >> 5;
        short8* F = (short8*)((char*)ws + WS_FRAG_OFF);

        short8 W1a;
#pragma unroll
        for (int j = 0; j < 8; ++j) {
            int p = q * 2 + (j >> 2), c = j & 3;
            W1a[j] = (c < 3) ? bf16rne(w1[ml * 27 + c * 9 + p]) : (short)0;
        }
        F[0 * 64 + lane] = W1a;

        short8 W1b;
#pragma unroll
        for (int j = 0; j < 8; ++j) {
            W1b[j] = (q == 0 && j < 3) ? bf16rne(w1[ml * 27 + j * 9 + 8])
                                       : (short)0;
        }
        F[1 * 64 + lane] = W1b;

#pragma unroll
        for (int s = 0; s < 9; ++s) {
            short8 Bs;
#pragma unroll
            for (int j = 0; j < 8; ++j) {
                int ic = half * 8 + j;
                Bs[j] = bf16rne(w2[(n32 * 16 + ic) * 9 + s]);
            }
            F[(2 + s) * 64 + lane] = Bs;
        }
        floatx4 bv;
#pragma unroll
        for (int r = 0; r < 4; ++r) bv[r] = b1[q * 4 + r];
        ((floatx4*)((char*)ws + WS_BIAS1_OFF))[lane] = bv;
        ((float*)((char*)ws + WS_BIAS2_OFF))[lane] = b2[n32];
    }
}

// compute half of a conv1 micro-tile from already-loaded gathers (by VALUE --
// never pass local arrays/vectors by pointer: address-taken -> scratch).
__device__ __forceinline__ void conv1_compute(
    char* __restrict__ wptr, int wbyte, bool valid, bool wmask,
    svec4 r0, svec4 r1, svec4 r2,
    short8 W1a, short8 W1b, floatx4 biasv)
{
    short8 Bx = __builtin_shufflevector(r0, r1, 0, 1, 2, 3, 4, 5, 6, 7);
    short8 By = __builtin_shufflevector(r2, r0, 0, 1, 2, 3, 4, 5, 6, 7);
    floatx4 acc = __builtin_amdgcn_mfma_f32_16x16x32_bf16(W1a, Bx, biasv,
                                                          0, 0, 0);
    acc = __builtin_amdgcn_mfma_f32_16x16x32_bf16(W1b, By, acc, 0, 0, 0);
    floatx2 lo = {acc[0], acc[1]}, hi = {acc[2], acc[3]};
    lo = pkmax0(lo); hi = pkmax0(hi);
    if (!valid) { floatx2 z = {0.f, 0.f}; lo = z; hi = z; }
    if (wmask) {
        uintx2 w; w.x = pk2(lo.x, lo.y); w.y = pk2(hi.x, hi.y);
        *(uintx2*)(wptr + wbyte) = w;
    }
}

// unpipelined single tile (col/corner units): load 3 gathers + compute.
__device__ __forceinline__ void conv1_tile(
    char* __restrict__ wptr, const char* __restrict__ inb,
    const int* lcB, int gbyte, int wbyte, bool valid, bool wmask,
    short8 W1a, short8 W1b, floatx4 biasv)
{
    svec4 r0 = *(const svec4*)(inb + gbyte + lcB[0]);
    svec4 r1 = *(const svec4*)(inb + gbyte + lcB[1]);
    svec4 r2 = *(const svec4*)(inb + gbyte + lcB[2]);
    conv1_compute(wptr, wbyte, valid, wmask, r0, r1, r2, W1a, W1b, biasv);
}

// ---------------------------------------------------------------------------
// Kernel A: 32x32 output tile per block. conv1+relu (2x 16x16x32 MFMA) ->
// conv2+relu (32x32x16 MFMA, 9-shift, sliding A-window) -> spatial sum ->
// atomicAdd feat_sum[B][32]. 256 threads = 4 waves, grid (8,8,64).
// r5 base (measured 69.0 us ~= 68.4 baseline) + conv1 2-stage software
// pipeline: tile i+1's 3 gathers issue before tile i's MFMA/pack/store,
// hiding the ~120cyc LDS latency chain (kernel is latency-bound at
// 3 waves/SIMD; issue slots only ~17% busy).
// ---------------------------------------------------------------------------
__global__ __launch_bounds__(256, 3) void conv_feat_kernel(
    const float* __restrict__ x,      // (64,3,256,256)
    const void*  __restrict__ ws_ro,
    float* __restrict__ feat_sum)     // (64,32)
{
    __shared__ short s_in4[36 * 36 * 4];   // bf16 [r][col][c pad4] (10368 B)
    __shared__ short s_h1[2 * 9248];       // two ic-half planes [pix][8] (36992 B)
    __shared__ float s_part[4][32];

    const int t    = threadIdx.x;
    const int lane = t & 63, wv = t >> 6;
    const int q    = lane >> 4, ml = lane & 15;
    const int n32  = lane & 31, half = lane >> 5;
    const int tx = blockIdx.x, ty = blockIdx.y, b = blockIdx.z;
    const bool border = (tx == 0) | (tx == 7) | (ty == 0) | (ty == 7);

    // ---- weight fragments / biases ----
    const short8* F = (const short8*)((const char*)ws_ro + WS_FRAG_OFF);
    short8 W1a = F[0 * 64 + lane];
    short8 W1b = F[1 * 64 + lane];
    short8 B2[9];
#pragma unroll
    for (int s = 0; s < 9; ++s) B2[s] = F[(2 + s) * 64 + lane];
    floatx4 biasv = ((const floatx4*)((const char*)ws_ro + WS_BIAS1_OFF))[lane];
    float   b2v   = ((const float*)((const char*)ws_ro + WS_BIAS2_OFF))[lane];

    // conv1 gather byte offsets (row stride 36 px * 8 B): positions q*2,q*2+1,8
    int lcB[3];
    {
        int p0 = q * 2, p1 = q * 2 + 1;
        lcB[0] = ((p0 / 3) * 36 + p0 % 3) * 8;
        lcB[1] = ((p1 / 3) * 36 + p1 % 3) * 8;
        lcB[2] = (2 * 36 + 2) * 8;
    }

    // ---- stage input tile as bf16 [r][col][4] (halo 2) ----
    const int gy0 = ty * 32 - 2, gx0 = tx * 32 - 2;
    const float* xb = x + (size_t)b * 3 * 65536;
    if (!border) {
        for (int i = t; i < 1296; i += 256) {
            int r = i / 36, c = i - r * 36;
            const float* p = xb + (gy0 + r) * 256 + gx0 + c;
            float v0 = p[0], v1 = p[65536], v2 = p[131072];
            uintx2 w; w.x = pk2(v0, v1); w.y = pk2(v2, 0.f);
            *(uintx2*)&s_in4[i * 4] = w;
        }
    } else {
        for (int i = t; i < 1296; i += 256) {
            int r = i / 36, c = i - r * 36;
            int gy = gy0 + r, gx = gx0 + c;
            float v0 = 0.f, v1 = 0.f, v2 = 0.f;
            if ((unsigned)gy < 256u && (unsigned)gx < 256u) {
                const float* p = xb + gy * 256 + gx;
                v0 = p[0]; v1 = p[65536]; v2 = p[131072];
            }
            uintx2 w; w.x = pk2(v0, v1); w.y = pk2(v2, 0.f);
            *(uintx2*)&s_in4[i * 4] = w;
        }
    }
    __syncthreads();

    // ---- conv1 over 34x34 h1: 68 row-units (2-stage pipelined) + 4 col
    //      units + corner. Gather addresses derive from the loop index only
    //      (independent; no serial address chain -> loads batch freely). ----
    char* wptr = (char*)s_h1 + (q >> 1) * PLANE_B + (q & 1) * 8;
    const char* inb = (const char*)s_in4;
    const int mlb = ml * 8, ml16 = ml * 16;
    if (!border) {
        svec4 a0, a1, a2;
        {
            int u = wv * 17, gb = (u >> 1) * 288 + (u & 1) * 128 + mlb;
            a0 = *(const svec4*)(inb + gb + lcB[0]);
            a1 = *(const svec4*)(inb + gb + lcB[1]);
            a2 = *(const svec4*)(inb + gb + lcB[2]);
        }
#pragma unroll
        for (int i = 0; i < 17; ++i) {
            int u = wv * 17 + i;
            int wb = (u >> 1) * 544 + (u & 1) * 256 + ml16;
            svec4 c0 = a0, c1 = a1, c2 = a2;
            if (i < 16) {
                int un = u + 1, gb = (un >> 1) * 288 + (un & 1) * 128 + mlb;
                a0 = *(const svec4*)(inb + gb + lcB[0]);
                a1 = *(const svec4*)(inb + gb + lcB[1]);
                a2 = *(const svec4*)(inb + gb + lcB[2]);
            }
            conv1_compute(wptr, wb, true, true, c0, c1, c2, W1a, W1b, biasv);
        }
        {   // col unit: col 32+(wv>>1), rows (wv&1)*16 + ml
            int col = 32 + (wv >> 1), rb = (wv & 1) * 16;
            conv1_tile(wptr, inb, lcB, (rb + ml) * 288 + col * 8,
                       ml * 544 + (rb * 34 + col) * 16, true, true,
                       W1a, W1b, biasv);
        }
        if (wv == 0) {   // corner 4 px: rows 32-33 x cols 32-33
            int ml2 = ml & 3;
            int iy = 32 + (ml2 >> 1), ix = 32 + (ml2 & 1);
            conv1_tile(wptr, inb, lcB, iy * 288 + ix * 8,
                       (iy * 34 + ix) * 16, true, ml < 4, W1a, W1b, biasv);
        }
    } else {
        const bool gxOK0 = (unsigned)(tx * 32 - 1 + ml) < 256u;
        const bool gxOK1 = (unsigned)(tx * 32 + 15 + ml) < 256u;
        svec4 a0, a1, a2;
        {
            int u = wv * 17, gb = (u >> 1) * 288 + (u & 1) * 128 + mlb;
            a0 = *(const svec4*)(inb + gb + lcB[0]);
            a1 = *(const svec4*)(inb + gb + lcB[1]);
            a2 = *(const svec4*)(inb + gb + lcB[2]);
        }
#pragma unroll
        for (int i = 0; i < 17; ++i) {
            int u = wv * 17 + i;
            int row = u >> 1, ch = u & 1;
            int wb = row * 544 + ch * 256 + ml16;
            bool ok = ((unsigned)(ty * 32 - 1 + row) < 256u) &
                      (ch ? gxOK1 : gxOK0);
            svec4 c0 = a0, c1 = a1, c2 = a2;
            if (i < 16) {
                int un = u + 1, gb = (un >> 1) * 288 + (un & 1) * 128 + mlb;
                a0 = *(const svec4*)(inb + gb + lcB[0]);
                a1 = *(const svec4*)(inb + gb + lcB[1]);
                a2 = *(const svec4*)(inb + gb + lcB[2]);
            }
            conv1_compute(wptr, wb, ok, true, c0, c1, c2, W1a, W1b, biasv);
        }
        {
            int col = 32 + (wv >> 1), rb = (wv & 1) * 16;
            bool ok = ((unsigned)(ty * 32 - 1 + rb + ml) < 256u) &
                      ((unsigned)(tx * 32 - 1 + col) < 256u);
            conv1_tile(wptr, inb, lcB, (rb + ml) * 288 + col * 8,
                       ml * 544 + (rb * 34 + col) * 16, ok, true,
                       W1a, W1b, biasv);
        }
        if (wv == 0) {
            int ml2 = ml & 3;
            int iy = 32 + (ml2 >> 1), ix = 32 + (ml2 & 1);
            bool ok = ((unsigned)(ty * 32 - 1 + iy) < 256u) &
                      ((unsigned)(tx * 32 - 1 + ix) < 256u);
            conv1_tile(wptr, inb, lcB, iy * 288 + ix * 8,
                       (iy * 34 + ix) * 16, ok, ml < 4, W1a, W1b, biasv);
        }
    }
    __syncthreads();

    // ---- conv2: wave = 8 vertically-chained 32-px tiles (2 rows x 16 cols),
    //      sliding 3x3 A-frag window (ky=2 row becomes next tile's ky=0) ----
    float part;
    {
        const int prow0 = n32 >> 4, pcol = n32 & 15;
        const int ch = wv >> 1, tp0 = (wv & 1) * 8;
        const int ox = ch * 16 + pcol;
        const char* pl = (const char*)s_h1 + half * PLANE_B;
        int pb = ((2 * tp0 + prow0) * 34 + ox) * 16;
        short8 Af[3][3];
#pragma unroll
        for (int ky = 0; ky < 3; ++ky)
#pragma unroll
            for (int kx = 0; kx < 3; ++kx)
                Af[ky][kx] = *(const short8*)(pl + pb + (ky * 34 + kx) * 16);

        floatx16 bias16;
#pragma unroll
        for (int r = 0; r < 16; ++r) bias16[r] = b2v;

        floatx2 p2 = {0.f, 0.f};
#pragma unroll
        for (int it = 0; it < 8; ++it) {
            const int rb = (2 * it) % 3;
            // s = 0 consumes the bias splat directly as the C operand
            floatx16 acc = __builtin_amdgcn_mfma_f32_32x32x16_bf16(
                    Af[rb][0], B2[0], bias16, 0, 0, 0);
#pragma unroll
            for (int s = 1; s < 9; ++s) {
                const int ky = s / 3, kx = s % 3;
                acc = __builtin_amdgcn_mfma_f32_32x32x16_bf16(
                        Af[(rb + ky) % 3][kx], B2[s], acc, 0, 0, 0);
            }
#pragma unroll
            for (int r = 0; r < 16; r += 2) {
                floatx2 a2 = {acc[r], acc[r + 1]};
                p2 += pkmax0(a2);      // v_pk_max_f32 + v_pk_add_f32
            }
            if (it < 7) {
                pb += 1088;   // advance 2 h1 rows
#pragma unroll
                for (int kx = 0; kx < 3; ++kx) {
                    Af[rb][kx] =
                        *(const short8*)(pl + pb + (1 * 34 + kx) * 16);
                    Af[(rb + 1) % 3][kx] =
                        *(const short8*)(pl + pb + (2 * 34 + kx) * 16);
                }
            }
        }
        part = p2.x + p2.y;
    }
    part += __shfl_xor(part, 32);
    if (lane < 32) s_part[wv][n32] = part;
    __syncthreads();
    if (t < 32) {
        float ssum = s_part[0][t] + s_part[1][t] + s_part[2][t] + s_part[3][t];
        atomicAdd(feat_sum + b * 32 + t, ssum);
    }
}

// ---------------------------------------------------------------------------
// Kernel B: gating. One block per batch row, 64 threads (= experts, 1 wave).
// ---------------------------------------------------------------------------
__global__ __launch_bounds__(64) void router_gate_kernel(
    const int* __restrict__ task_id,
    const float* __restrict__ noise,
    const float* __restrict__ mlp_w1,
    const float* __restrict__ mlp_b1,
    const float* __restrict__ mlp_w2,
    const float* __restrict__ mlp_b2,
    const float* __restrict__ deg_w,
    const float* __restrict__ deg_b,
    const float* __restrict__ keys,
    const float* __restrict__ gate_w,
    const float* __restrict__ gate_b,
    const float* __restrict__ noise_w,
    const float* __restrict__ noise_b,
    const float* __restrict__ feat_sum,
    float* __restrict__ out)
{
    const int b = blockIdx.x;
    const int e = threadIdx.x;

    __shared__ float s_te[32];
    __shared__ float s_comb[32];
    __shared__ float s_ew[64];

    if (e < 32) {
        float tf = (float)task_id[b];
        s_te[e] = fmaxf(tf * mlp_w1[e] + mlp_b1[e], 0.0f);
    }
    __syncthreads();
    if (e < 32) {
        float acc = mlp_b2[e];
        for (int k = 0; k < 32; ++k) acc += s_te[k] * mlp_w2[k * 32 + e];
        float dacc = deg_b[e];
        for (int c = 0; c < 32; ++c)
            dacc += (feat_sum[b * 32 + c] * (1.0f / 65536.0f)) * deg_w[c * 32 + e];
        s_comb[e] = acc + 0.2f * dacc;  // ALPHA = 0.8
    }
    __syncthreads();

    float s = 0.0f;
    for (int d = 0; d < 32; ++d) s += s_comb[d] * keys[e * 32 + d];
    s *= 0.17677669529663687f;  // 1/sqrt(32)

    float m = s;
    for (int off = 32; off; off >>= 1) m = fmaxf(m, __shfl_xor(m, off));
    float p = expf(s - m);
    float sum = p;
    for (int off = 32; off; off >>= 1) sum += __shfl_xor(sum, off);
    float w = p / sum;
    s_ew[e] = w;
    __syncthreads();

    float cl = gate_b[e], nz = noise_b[e];
    for (int k = 0; k < 64; ++k) {
        float ewk = s_ew[k];
        cl += ewk * gate_w[k * 64 + e];
        nz += ewk * noise_w[k * 64 + e];
    }
    float sp = (nz > 20.0f) ? nz : log1pf(expf(nz));
    float logit = cl + noise[b * 64 + e] * (sp + 0.01f);

    float v0 = logit; int i0 = e;
    for (int off = 32; off; off >>= 1) {
        float ov = __shfl_xor(v0, off);
        int   oi = __shfl_xor(i0, off);
        if (ov > v0 || (ov == v0 && oi < i0)) { v0 = ov; i0 = oi; }
    }
    float v1 = (e == i0) ? -INFINITY : logit; int i1 = e;
    for (int off = 32; off; off >>= 1) {
        float ov = __shfl_xor(v1, off);
        int   oi = __shfl_xor(i1, off);
        if (ov > v1 || (ov == v1 && oi < i1)) { v1 = ov; i1 = oi; }
    }

    float e1 = expf(v1 - v0);
    float g0 = 1.0f / (1.0f + e1);
    float g1 = e1 / (1.0f + e1);

    float g = (e == i0) ? g0 : (e == i1) ? g1 : 0.0f;
    out[b * 64 + e] = g;
    if (g != 0.0f) atomicAdd(out + 64 * 64 + e, g);
}

extern "C" void kernel_launch(void* const* d_in, const int* in_sizes, int n_in,
                              void* d_out, int out_size, void* d_ws, size_t ws_size,
                              hipStream_t stream) {
    const int*   task_id = (const int*)d_in[0];
    const float* x       = (const float*)d_in[1];
    const float* noise   = (const float*)d_in[2];
    const float* mlp_w1  = (const float*)d_in[3];
    const float* mlp_b1  = (const float*)d_in[4];
    const float* mlp_w2  = (const float*)d_in[5];
    const float* mlp_b2  = (const float*)d_in[6];
    const float* conv1_w = (const float*)d_in[7];
    const float* conv1_b = (const float*)d_in[8];
    const float* conv2_w = (const float*)d_in[9];
    const float* conv2_b = (const float*)d_in[10];
    const float* deg_w   = (const float*)d_in[11];
    const float* deg_b   = (const float*)d_in[12];
    const float* keys    = (const float*)d_in[13];
    const float* gate_w  = (const float*)d_in[14];
    const float* gate_b  = (const float*)d_in[15];
    const float* noise_w = (const float*)d_in[16];
    const float* noise_b = (const float*)d_in[17];

    float* out  = (float*)d_out;
    float* feat = (float*)d_ws;

    build_frags_kernel<<<1, 256, 0, stream>>>(conv1_w, conv1_b, conv2_w,
                                              conv2_b, d_ws, out);
    dim3 gridA(8, 8, 64);
    conv_feat_kernel<<<gridA, 256, 0, stream>>>(x, d_ws, feat);
    router_gate_kernel<<<64, 64, 0, stream>>>(
        task_id, noise, mlp_w1, mlp_b1, mlp_w2, mlp_b2, deg_w, deg_b, keys,
        gate_w, gate_b, noise_w, noise_b, feat, out);
}